// Round 13
// baseline (1259.231 us; speedup 1.0000x reference)
//
#include <hip/hip_runtime.h>
#include <stdint.h>

#define BATCH 512
#define SEQ   512
#define HID   128
#define BT    16        // batch tile per chain
#define XROW  272       // LDS row stride bytes (128 f16 data + 16B pad)
#define XSZ   (BT*XROW) // 4352B per buffer
#define NPAIR 16        // pair-blocks per layer (2 chains = 32 batch each)
#define CH    8         // steps per done-chunk (back-pressure only)
#define RING  64        // ring slots (steps) per layer boundary
#define FPAD  32        // ints per flag (128B line)
#define SKEW  8         // startup lag consumers establish vs producer

typedef _Float16 half8 __attribute__((ext_vector_type(8)));
typedef float f32x4 __attribute__((ext_vector_type(4)));
typedef unsigned long long u64;

// In-loop barrier without vmcnt drain: only LDS handoff must be visible.
#define BARRIER_LDS() do { \
    asm volatile("s_waitcnt lgkmcnt(0)" ::: "memory"); \
    __builtin_amdgcn_s_barrier(); \
  } while(0)

union UHP { uint32_t u; _Float16 h[2]; };
__device__ __forceinline__ uint32_t pack2f(float a, float b){
  UHP r; r.h[0] = (_Float16)a; r.h[1] = (_Float16)b; return r.u;
}
__device__ __forceinline__ float unpk(uint32_t u, int i){
  UHP r; r.u = u; return (float)r.h[i];
}

__device__ __forceinline__ float rcp_(float x){
#if __has_builtin(__builtin_amdgcn_rcpf)
  return __builtin_amdgcn_rcpf(x);
#else
  return 1.f / x;
#endif
}
__device__ __forceinline__ float exp2_(float x){
#if __has_builtin(__builtin_amdgcn_exp2f)
  return __builtin_amdgcn_exp2f(x);
#else
  return exp2f(x);
#endif
}
__device__ __forceinline__ float sigm(float x){ return rcp_(1.f + exp2_(x * -1.44269504f)); }
__device__ __forceinline__ float tanh_(float x){ return 1.f - 2.f * rcp_(exp2_(x * 2.88539008f) + 1.f); }

__device__ __forceinline__ int aload(const int* p){
  return __hip_atomic_load(p, __ATOMIC_RELAXED, __HIP_MEMORY_SCOPE_AGENT);
}

// MODE 0: x fp32 -> ring0 ; MODE 1: ring0 -> ring1 ; MODE 2: ring1 -> y fp32
// Round-13 = round-12 kernel (two chains per wave, shared weights) with the
// ONE change: __launch_bounds__(512, 1). Min 1 wave/EU -> 512-VGPR budget ->
// allocator free to keep the ~240 live regs (round 12's (512,2) stuck at 128
// and spilled ~100 regs to scratch, 2x step latency).
template<int MODE>
__device__ __forceinline__ void run_layer(
    const float* __restrict__ Wih, const float* __restrict__ Whh,
    const float* __restrict__ bih, const float* __restrict__ bhh,
    const float* __restrict__ x, uint32_t* __restrict__ rin,
    uint32_t* __restrict__ rout, float* __restrict__ y,
    int* src_ready, int* src_done, int* dst_ready, int* dst_done,
    int b0A, int b0B,
    char* xbA, char* hbA, char* xbB, char* hbB)
{
  const int tid  = threadIdx.x;
  const int lane = tid & 63;
  const int w    = tid >> 6;
  const int u0   = w * 16;
  const int rm   = lane & 15;   // batch col within tile
  const int kq   = lane >> 4;   // k-quarter / acc row group

  // ---- weights (SHARED by both chains) -> f16 register fragments
  half8 wih[4][4], whh[4][4];
  #pragma unroll
  for (int g = 0; g < 4; ++g){
    const int grow = g * HID + u0 + rm;
    #pragma unroll
    for (int s = 0; s < 4; ++s){
      const int k = s * 32 + kq * 8;
      const float* si = Wih + (size_t)grow * HID + k;
      const float* sh = Whh + (size_t)grow * HID + k;
      float4 aa = *(const float4*)si, bb = *(const float4*)(si + 4);
      half8 hi;
      hi[0]=(_Float16)aa.x; hi[1]=(_Float16)aa.y; hi[2]=(_Float16)aa.z; hi[3]=(_Float16)aa.w;
      hi[4]=(_Float16)bb.x; hi[5]=(_Float16)bb.y; hi[6]=(_Float16)bb.z; hi[7]=(_Float16)bb.w;
      wih[g][s] = hi;
      aa = *(const float4*)sh; bb = *(const float4*)(sh + 4);
      half8 hh;
      hh[0]=(_Float16)aa.x; hh[1]=(_Float16)aa.y; hh[2]=(_Float16)aa.z; hh[3]=(_Float16)aa.w;
      hh[4]=(_Float16)bb.x; hh[5]=(_Float16)bb.y; hh[6]=(_Float16)bb.z; hh[7]=(_Float16)bb.w;
      whh[g][s] = hh;
    }
  }
  f32x4 bias4[4];
  #pragma unroll
  for (int g = 0; g < 4; ++g)
    #pragma unroll
    for (int r = 0; r < 4; ++r){
      const int row = g * HID + u0 + kq * 4 + r;
      bias4[g][r] = bih[row] + bhh[row];
    }

  // ---- staging thread mapping: 16 rows x 128 f16 (per chain)
  const int sb = tid >> 5;   // 0..15 batch row
  const int sk = tid & 31;   // col group (8B)

  auto xaddrA = [&](int t){
    return (const float4*)(x + ((size_t)(b0A + sb) * SEQ + t) * HID + sk * 4);
  };
  auto xaddrB = [&](int t){
    return (const float4*)(x + ((size_t)(b0B + sb) * SEQ + t) * HID + sk * 4);
  };
  auto raddrA = [&](int t){
    return (u64*)(rin + ((size_t)(t & (RING-1)) * BATCH + b0A + sb) * 64 + sk * 2);
  };
  auto raddrB = [&](int t){
    return (u64*)(rin + ((size_t)(t & (RING-1)) * BATCH + b0B + sb) * 64 + sk * 2);
  };

  float4 pfaA, pfbA, pfaB, pfbB;          // MODE 0 prefetch
  u64    pgaA = 0, pgbA = 0, pgaB = 0, pgbB = 0;  // MODE 1/2 prefetch

  int fseen = 0, fpend = 0, dseen = 0;

  // ---- prologue: SKEW lag, stage t=0,1 both chains, preload t=2
  if constexpr (MODE != 0){
    fseen = aload(src_ready);
    while (fseen < SKEW){ __builtin_amdgcn_s_sleep(8); fseen = aload(src_ready); }
  }
  if constexpr (MODE == 0){
    float4 v = *xaddrA(0);
    uint2 p; p.x = pack2f(v.x, v.y); p.y = pack2f(v.z, v.w);
    *(uint2*)(xbA + sb * XROW + sk * 8) = p;
    v = *xaddrB(0);
    p.x = pack2f(v.x, v.y); p.y = pack2f(v.z, v.w);
    *(uint2*)(xbB + sb * XROW + sk * 8) = p;
    v = *xaddrA(1);
    p.x = pack2f(v.x, v.y); p.y = pack2f(v.z, v.w);
    *(uint2*)(xbA + XSZ + sb * XROW + sk * 8) = p;
    v = *xaddrB(1);
    p.x = pack2f(v.x, v.y); p.y = pack2f(v.z, v.w);
    *(uint2*)(xbB + XSZ + sb * XROW + sk * 8) = p;
    pfaA = *xaddrA(2);
    pfaB = *xaddrB(2);
  } else {
    u64 v = __hip_atomic_load(raddrA(0), __ATOMIC_RELAXED, __HIP_MEMORY_SCOPE_AGENT);
    *(u64*)(xbA + sb * XROW + sk * 8) = v;
    v = __hip_atomic_load(raddrB(0), __ATOMIC_RELAXED, __HIP_MEMORY_SCOPE_AGENT);
    *(u64*)(xbB + sb * XROW + sk * 8) = v;
    v = __hip_atomic_load(raddrA(1), __ATOMIC_RELAXED, __HIP_MEMORY_SCOPE_AGENT);
    *(u64*)(xbA + XSZ + sb * XROW + sk * 8) = v;
    v = __hip_atomic_load(raddrB(1), __ATOMIC_RELAXED, __HIP_MEMORY_SCOPE_AGENT);
    *(u64*)(xbB + XSZ + sb * XROW + sk * 8) = v;
    pgaA = __hip_atomic_load(raddrA(2), __ATOMIC_RELAXED, __HIP_MEMORY_SCOPE_AGENT);
    pgaB = __hip_atomic_load(raddrB(2), __ATOMIC_RELAXED, __HIP_MEMORY_SCOPE_AGENT);
    fpend = aload(src_ready);
  }
  if (tid < 256){
    *(uint4*)(hbA + (tid >> 4) * XROW + (tid & 15) * 16) = make_uint4(0u,0u,0u,0u);
    *(uint4*)(hbB + (tid >> 4) * XROW + (tid & 15) * 16) = make_uint4(0u,0u,0u,0u);
  }
  __syncthreads();   // prologue: full drain once

  // ---- acc init for t=0: bias + Wih*x(0), both chains
  const int foff = rm * XROW + kq * 16;
  f32x4 aA0 = bias4[0], aA1 = bias4[1], aA2 = bias4[2], aA3 = bias4[3];
  f32x4 aB0 = bias4[0], aB1 = bias4[1], aB2 = bias4[2], aB3 = bias4[3];
  #pragma unroll
  for (int s = 0; s < 4; ++s){
    const half8 bfA = *(const half8*)(xbA + foff + s * 64);
    const half8 bfB = *(const half8*)(xbB + foff + s * 64);
    aA0 = __builtin_amdgcn_mfma_f32_16x16x32_f16(wih[0][s], bfA, aA0, 0, 0, 0);
    aB0 = __builtin_amdgcn_mfma_f32_16x16x32_f16(wih[0][s], bfB, aB0, 0, 0, 0);
    aA1 = __builtin_amdgcn_mfma_f32_16x16x32_f16(wih[1][s], bfA, aA1, 0, 0, 0);
    aB1 = __builtin_amdgcn_mfma_f32_16x16x32_f16(wih[1][s], bfB, aB1, 0, 0, 0);
    aA2 = __builtin_amdgcn_mfma_f32_16x16x32_f16(wih[2][s], bfA, aA2, 0, 0, 0);
    aB2 = __builtin_amdgcn_mfma_f32_16x16x32_f16(wih[2][s], bfB, aB2, 0, 0, 0);
    aA3 = __builtin_amdgcn_mfma_f32_16x16x32_f16(wih[3][s], bfA, aA3, 0, 0, 0);
    aB3 = __builtin_amdgcn_mfma_f32_16x16x32_f16(wih[3][s], bfB, aB3, 0, 0, 0);
  }

  f32x4 cA = {0.f,0.f,0.f,0.f}, cB = {0.f,0.f,0.f,0.f};
  int cur = 0, xr = 1, xw = 2;
  uint2 hpA = {0u,0u}, hpB = {0u,0u};

  for (int t = 0; t < SEQ; ++t){
    char* hbcA = hbA + cur * XSZ;        char* hbcB = hbB + cur * XSZ;
    char* hbnA = hbA + (cur ^ 1) * XSZ;  char* hbnB = hbB + (cur ^ 1) * XSZ;
    char* xbrA = xbA + xr * XSZ;         char* xbrB = xbB + xr * XSZ;
    char* xbwA = xbA + xw * XSZ;         char* xbwB = xbB + xw * XSZ;
    const int tn = t + 1;

    // ---- flush deferred global stores of h(t-1), both chains
    if (t > 0){
      if constexpr (MODE != 2){
        const u64 hA = ((u64)hpA.y << 32) | (u64)hpA.x;
        const u64 hB = ((u64)hpB.y << 32) | (u64)hpB.x;
        u64* pA = (u64*)(rout + ((size_t)((t-1) & (RING-1)) * BATCH + b0A + rm) * 64 + (u0 >> 1) + kq * 2);
        u64* pB = (u64*)(rout + ((size_t)((t-1) & (RING-1)) * BATCH + b0B + rm) * 64 + (u0 >> 1) + kq * 2);
        __hip_atomic_store(pA, hA, __ATOMIC_RELAXED, __HIP_MEMORY_SCOPE_AGENT);
        __hip_atomic_store(pB, hB, __ATOMIC_RELAXED, __HIP_MEMORY_SCOPE_AGENT);
      } else {
        const size_t ybA = ((size_t)(t-1) * HID + u0 + kq * 4) * BATCH + b0A + rm;
        const size_t ybB = ((size_t)(t-1) * HID + u0 + kq * 4) * BATCH + b0B + rm;
        y[ybA]             = unpk(hpA.x, 0);
        y[ybA + BATCH]     = unpk(hpA.x, 1);
        y[ybA + 2 * BATCH] = unpk(hpA.y, 0);
        y[ybA + 3 * BATCH] = unpk(hpA.y, 1);
        y[ybB]             = unpk(hpB.x, 0);
        y[ybB + BATCH]     = unpk(hpB.x, 1);
        y[ybB + 2 * BATCH] = unpk(hpB.y, 0);
        y[ybB + 3 * BATCH] = unpk(hpB.y, 1);
      }
    }
    // ---- continuous ready publish: value t-2 (stores issued >=1.5 steps ago)
    if (tid == 0){
      if constexpr (MODE != 2){
        if (t >= 3)
          __hip_atomic_store(dst_ready, t - 2, __ATOMIC_RELAXED, __HIP_MEMORY_SCOPE_AGENT);
      }
      if constexpr (MODE != 0){
        if ((t & (CH-1)) == 0 && t > 0)
          __hip_atomic_store(src_done, t >> 3, __ATOMIC_RELAXED, __HIP_MEMORY_SCOPE_AGENT);
      }
    }
    // ---- back-pressure: cached; blocking refresh only if bound violated
    if constexpr (MODE != 2){
      if ((t & (CH-1)) == 0 && t >= RING){
        const int need = (t >> 3) - 7;
        if (dseen < need){
          dseen = aload(dst_done);
          while (dseen < need){ __builtin_amdgcn_s_sleep(8); dseen = aload(dst_done); }
        }
      }
    }
    // ---- pipelined flag check (one flag serves both chains)
    if constexpr (MODE != 0){
      if (fpend > fseen) fseen = fpend;
      fpend = aload(src_ready);
      if (t + 3 < SEQ && fseen < t + 4){
        fseen = aload(src_ready);
        while (fseen < t + 4){ __builtin_amdgcn_s_sleep(2); fseen = aload(src_ready); }
      }
    }
    if (t + 3 < SEQ){
      if constexpr (MODE == 0){
        pfbA = *xaddrA(t + 3);
        pfbB = *xaddrB(t + 3);
      } else {
        pgbA = __hip_atomic_load(raddrA(t + 3), __ATOMIC_RELAXED, __HIP_MEMORY_SCOPE_AGENT);
        pgbB = __hip_atomic_load(raddrB(t + 3), __ATOMIC_RELAXED, __HIP_MEMORY_SCOPE_AGENT);
      }
    }

    // ---- CRITICAL: acc += Whh*h(t-1), both chains interleaved (ILP)
    #pragma unroll
    for (int s = 0; s < 4; ++s){
      const half8 bfA = *(const half8*)(hbcA + foff + s * 64);
      const half8 bfB = *(const half8*)(hbcB + foff + s * 64);
      aA0 = __builtin_amdgcn_mfma_f32_16x16x32_f16(whh[0][s], bfA, aA0, 0, 0, 0);
      aB0 = __builtin_amdgcn_mfma_f32_16x16x32_f16(whh[0][s], bfB, aB0, 0, 0, 0);
      aA1 = __builtin_amdgcn_mfma_f32_16x16x32_f16(whh[1][s], bfA, aA1, 0, 0, 0);
      aB1 = __builtin_amdgcn_mfma_f32_16x16x32_f16(whh[1][s], bfB, aB1, 0, 0, 0);
      aA2 = __builtin_amdgcn_mfma_f32_16x16x32_f16(whh[2][s], bfA, aA2, 0, 0, 0);
      aB2 = __builtin_amdgcn_mfma_f32_16x16x32_f16(whh[2][s], bfB, aB2, 0, 0, 0);
      aA3 = __builtin_amdgcn_mfma_f32_16x16x32_f16(whh[3][s], bfA, aA3, 0, 0, 0);
      aB3 = __builtin_amdgcn_mfma_f32_16x16x32_f16(whh[3][s], bfB, aB3, 0, 0, 0);
    }

    // ---- elementwise, both chains (two independent trans chains)
    {
      float hvA[4], hvB[4];
      #pragma unroll
      for (int r = 0; r < 4; ++r){
        const float iiA = sigm(aA0[r]), ffA = sigm(aA1[r]);
        const float ggA = tanh_(aA2[r]), ooA = sigm(aA3[r]);
        const float iiB = sigm(aB0[r]), ffB = sigm(aB1[r]);
        const float ggB = tanh_(aB2[r]), ooB = sigm(aB3[r]);
        cA[r] = ffA * cA[r] + iiA * ggA;
        cB[r] = ffB * cB[r] + iiB * ggB;
        hvA[r] = ooA * tanh_(cA[r]);
        hvB[r] = ooB * tanh_(cB[r]);
      }
      hpA.x = pack2f(hvA[0], hvA[1]);  hpA.y = pack2f(hvA[2], hvA[3]);
      hpB.x = pack2f(hvB[0], hvB[1]);  hpB.y = pack2f(hvB[2], hvB[3]);
    }

    // ---- h(t) -> LDS, both chains
    *(uint2*)(hbnA + rm * XROW + u0 * 2 + kq * 8) = hpA;
    *(uint2*)(hbnB + rm * XROW + u0 * 2 + kq * 8) = hpB;

    // ---- stage x(t+2) -> write buffers
    if (t + 2 < SEQ){
      if constexpr (MODE == 0){
        uint2 p;
        p.x = pack2f(pfaA.x, pfaA.y); p.y = pack2f(pfaA.z, pfaA.w);
        *(uint2*)(xbwA + sb * XROW + sk * 8) = p;
        p.x = pack2f(pfaB.x, pfaB.y); p.y = pack2f(pfaB.z, pfaB.w);
        *(uint2*)(xbwB + sb * XROW + sk * 8) = p;
      } else {
        *(u64*)(xbwA + sb * XROW + sk * 8) = pgaA;
        *(u64*)(xbwB + sb * XROW + sk * 8) = pgaB;
      }
    }

    // ---- OFF-PATH: acc = bias + Wih*x(t+1), both chains
    if (tn < SEQ){
      aA0 = bias4[0]; aA1 = bias4[1]; aA2 = bias4[2]; aA3 = bias4[3];
      aB0 = bias4[0]; aB1 = bias4[1]; aB2 = bias4[2]; aB3 = bias4[3];
      #pragma unroll
      for (int s = 0; s < 4; ++s){
        const half8 bfA = *(const half8*)(xbrA + foff + s * 64);
        const half8 bfB = *(const half8*)(xbrB + foff + s * 64);
        aA0 = __builtin_amdgcn_mfma_f32_16x16x32_f16(wih[0][s], bfA, aA0, 0, 0, 0);
        aB0 = __builtin_amdgcn_mfma_f32_16x16x32_f16(wih[0][s], bfB, aB0, 0, 0, 0);
        aA1 = __builtin_amdgcn_mfma_f32_16x16x32_f16(wih[1][s], bfA, aA1, 0, 0, 0);
        aB1 = __builtin_amdgcn_mfma_f32_16x16x32_f16(wih[1][s], bfB, aB1, 0, 0, 0);
        aA2 = __builtin_amdgcn_mfma_f32_16x16x32_f16(wih[2][s], bfA, aA2, 0, 0, 0);
        aB2 = __builtin_amdgcn_mfma_f32_16x16x32_f16(wih[2][s], bfB, aB2, 0, 0, 0);
        aA3 = __builtin_amdgcn_mfma_f32_16x16x32_f16(wih[3][s], bfA, aA3, 0, 0, 0);
        aB3 = __builtin_amdgcn_mfma_f32_16x16x32_f16(wih[3][s], bfB, aB3, 0, 0, 0);
      }
    }

    BARRIER_LDS();
    pfaA = pfbA; pfaB = pfbB; pgaA = pgbA; pgaB = pgbB;
    xr = (xr == 2) ? 0 : xr + 1;
    xw = (xw == 2) ? 0 : xw + 1;
    cur ^= 1;
  }

  // ---- tail: flush step SEQ-1 both chains, full drain, final publishes
  if constexpr (MODE != 2){
    const u64 hA = ((u64)hpA.y << 32) | (u64)hpA.x;
    const u64 hB = ((u64)hpB.y << 32) | (u64)hpB.x;
    u64* pA = (u64*)(rout + ((size_t)((SEQ-1) & (RING-1)) * BATCH + b0A + rm) * 64 + (u0 >> 1) + kq * 2);
    u64* pB = (u64*)(rout + ((size_t)((SEQ-1) & (RING-1)) * BATCH + b0B + rm) * 64 + (u0 >> 1) + kq * 2);
    __hip_atomic_store(pA, hA, __ATOMIC_RELAXED, __HIP_MEMORY_SCOPE_AGENT);
    __hip_atomic_store(pB, hB, __ATOMIC_RELAXED, __HIP_MEMORY_SCOPE_AGENT);
  } else {
    const size_t ybA = ((size_t)(SEQ-1) * HID + u0 + kq * 4) * BATCH + b0A + rm;
    const size_t ybB = ((size_t)(SEQ-1) * HID + u0 + kq * 4) * BATCH + b0B + rm;
    y[ybA]             = unpk(hpA.x, 0);
    y[ybA + BATCH]     = unpk(hpA.x, 1);
    y[ybA + 2 * BATCH] = unpk(hpA.y, 0);
    y[ybA + 3 * BATCH] = unpk(hpA.y, 1);
    y[ybB]             = unpk(hpB.x, 0);
    y[ybB + BATCH]     = unpk(hpB.x, 1);
    y[ybB + 2 * BATCH] = unpk(hpB.y, 0);
    y[ybB + 3 * BATCH] = unpk(hpB.y, 1);
  }
  __syncthreads();   // tail: FULL drain -> final flags valid
  if (tid == 0){
    if constexpr (MODE != 2)
      __hip_atomic_store(dst_ready, SEQ, __ATOMIC_RELAXED, __HIP_MEMORY_SCOPE_AGENT);
    if constexpr (MODE != 0)
      __hip_atomic_store(src_done, SEQ / CH, __ATOMIC_RELAXED, __HIP_MEMORY_SCOPE_AGENT);
  }
}

// Grid: 48 blocks (3 layers x 16 pairs) x 512 threads.
// __launch_bounds__(512, 1): min 1 wave/EU -> VGPR budget 512; the kernel
// needs ~240, which still permits 2 waves/SIMD in hardware. ((512,2) capped
// the allocator at 128 -> ~100 spilled regs -> 2x step latency, round 12.)
__global__ __launch_bounds__(512, 1) void lstm_pipe(
    const float* W0i, const float* W0h, const float* b0i, const float* b0h,
    const float* W1i, const float* W1h, const float* b1i, const float* b1h,
    const float* W2i, const float* W2h, const float* b2i, const float* b2h,
    const float* x, float* y, uint32_t* ring, int* flags)
{
  const int layer = blockIdx.x / NPAIR;        // 0,1,2
  const int pair  = blockIdx.x % NPAIR;
  const int b0A   = pair * 2 * BT;
  const int b0B   = b0A + BT;

  __shared__ char smem[10 * XSZ];      // per chain: xb[3] + hb[2]
  char* xbA = smem;
  char* hbA = smem + 3 * XSZ;
  char* xbB = smem + 5 * XSZ;
  char* hbB = smem + 8 * XSZ;

  uint32_t* r0 = ring;                                 // boundary 0: L0 -> L1
  uint32_t* r1 = ring + (size_t)RING * BATCH * 64;     // boundary 1: L1 -> L2

  // flags per PAIR (both chains produced/consumed in lockstep)
  int* p0 = flags + (0 * NPAIR + pair) * FPAD;   // ready, boundary 0
  int* p1 = flags + (1 * NPAIR + pair) * FPAD;   // ready, boundary 1
  int* c0 = flags + (2 * NPAIR + pair) * FPAD;   // done,  boundary 0
  int* c1 = flags + (3 * NPAIR + pair) * FPAD;   // done,  boundary 1

  if (layer == 0){
    run_layer<0>(W0i, W0h, b0i, b0h, x, nullptr, r0, nullptr,
                 nullptr, nullptr, p0, c0, b0A, b0B, xbA, hbA, xbB, hbB);
  } else if (layer == 1){
    run_layer<1>(W1i, W1h, b1i, b1h, nullptr, r0, r1, nullptr,
                 p0, c0, p1, c1, b0A, b0B, xbA, hbA, xbB, hbB);
  } else {
    run_layer<2>(W2i, W2h, b2i, b2h, nullptr, r1, nullptr, y,
                 p1, c1, nullptr, nullptr, b0A, b0B, xbA, hbA, xbB, hbB);
  }
}

extern "C" void kernel_launch(void* const* d_in, const int* in_sizes, int n_in,
                              void* d_out, int out_size, void* d_ws, size_t ws_size,
                              hipStream_t stream) {
  const float* x    = (const float*)d_in[0];
  const float* Wih0 = (const float*)d_in[1];
  const float* Whh0 = (const float*)d_in[2];
  const float* bih0 = (const float*)d_in[3];
  const float* bhh0 = (const float*)d_in[4];
  const float* Wih1 = (const float*)d_in[5];
  const float* Whh1 = (const float*)d_in[6];
  const float* bih1 = (const float*)d_in[7];
  const float* bhh1 = (const float*)d_in[8];
  const float* Wih2 = (const float*)d_in[9];
  const float* Whh2 = (const float*)d_in[10];
  const float* bih2 = (const float*)d_in[11];
  const float* bhh2 = (const float*)d_in[12];

  float* out = (float*)d_out;
  uint32_t* ring = (uint32_t*)d_ws;
  const size_t ring_bytes = (size_t)2 * RING * BATCH * 64 * 4;   // 16 MiB
  int* flags = (int*)((char*)d_ws + ring_bytes);

  hipMemsetAsync(flags, 0, 4 * NPAIR * FPAD * sizeof(int), stream);

  dim3 grid(3 * NPAIR), block(512);
  lstm_pipe<<<grid, block, 0, stream>>>(
      Wih0, Whh0, bih0, bhh0, Wih1, Whh1, bih1, bhh1, Wih2, Whh2, bih2, bhh2,
      x, out, ring, flags);
}

// Round 14
// 651.661 us; speedup vs baseline: 1.9323x; 1.9323x over previous
//
#include <hip/hip_runtime.h>
#include <stdint.h>

#define BATCH 512
#define SEQ   512
#define HID   128
#define BT    16        // batch tile per block
#define ROWB  528       // LDS act row stride in bytes
#define NTILE 32        // BATCH/BT
#define CH    8         // steps per done-chunk (back-pressure only)
#define RING  64        // ring slots (steps) per layer boundary
#define FPAD  32        // ints per flag (128B line)
#define SKEW  8         // startup lag consumers establish vs producer

typedef _Float16 half8 __attribute__((ext_vector_type(8)));
typedef float f32x4 __attribute__((ext_vector_type(4)));
typedef unsigned long long u64;

// In-loop barrier without vmcnt drain: only LDS handoff must be visible
// (measured neutral vs __syncthreads in r11, kept for the publish margin).
#define BARRIER_LDS() do { \
    asm volatile("s_waitcnt lgkmcnt(0)" ::: "memory"); \
    __builtin_amdgcn_s_barrier(); \
  } while(0)

union UHP { uint32_t u; _Float16 h[2]; };
__device__ __forceinline__ uint32_t pack2f(float a, float b){
  UHP r; r.h[0] = (_Float16)a; r.h[1] = (_Float16)b; return r.u;
}
__device__ __forceinline__ float unpk(uint32_t u, int i){
  UHP r; r.u = u; return (float)r.h[i];
}

__device__ __forceinline__ float rcp_(float x){
#if __has_builtin(__builtin_amdgcn_rcpf)
  return __builtin_amdgcn_rcpf(x);
#else
  return 1.f / x;
#endif
}
__device__ __forceinline__ float exp2_(float x){
#if __has_builtin(__builtin_amdgcn_exp2f)
  return __builtin_amdgcn_exp2f(x);
#else
  return exp2f(x);
#endif
}
__device__ __forceinline__ float sigm(float x){ return rcp_(1.f + exp2_(x * -1.44269504f)); }
__device__ __forceinline__ float tanh_(float x){ return 1.f - 2.f * rcp_(exp2_(x * 2.88539008f) + 1.f); }

__device__ __forceinline__ int aload(const int* p){
  return __hip_atomic_load(p, __ATOMIC_RELAXED, __HIP_MEMORY_SCOPE_AGENT);
}

// MODE 0: x fp32 -> ring0 ; MODE 1: ring0 -> ring1 ; MODE 2: ring1 -> y fp32
//
// Round-14 = round-8 fused structure (658us, best measured) with
// register-neutral intra-step phase packing:
//   top:    all VMEM issue (deferred store, flag pipeline, 2-deep prefetch)
//   mid:    fused K=256 MFMA loop (LDS read burst + matrix pipe)
//   then:   x(t+1) staging writes  <- moved HERE: LDS pipe is idle during
//           the following transcendental burst, writes drain for free
//   then:   elementwise (trans burst) + h(t) LDS write
//   barrier (lgkm-only)
// setprio(1) wraps MFMA+ew: waves drift mid-step (LDS queue staggers them),
// so compute-phase waves get scheduler preference over issue-phase waves.
template<int MODE>
__device__ __forceinline__ void run_layer(
    const float* __restrict__ Wih, const float* __restrict__ Whh,
    const float* __restrict__ bih, const float* __restrict__ bhh,
    const float* __restrict__ x, uint32_t* __restrict__ rin,
    uint32_t* __restrict__ rout, float* __restrict__ y,
    int* src_ready, int* src_done, int* dst_ready, int* dst_done,
    int b0, char* act0, char* act1)
{
  const int tid  = threadIdx.x;
  const int lane = tid & 63;
  const int w    = tid >> 6;
  const int u0   = w * 16;
  const int rm   = lane & 15;   // batch col within tile
  const int kq   = lane >> 4;   // k-quarter / acc row group

  // ---- weights -> f16 register fragments (fused K=256: s<4 Wih, s>=4 Whh)
  half8 wf[4][8];
  #pragma unroll
  for (int g = 0; g < 4; ++g){
    const int grow = g * HID + u0 + rm;
    #pragma unroll
    for (int s = 0; s < 8; ++s){
      const int k = s * 32 + kq * 8;
      const float* src = (s < 4) ? (Wih + (size_t)grow * HID + k)
                                 : (Whh + (size_t)grow * HID + (k - HID));
      const float4 aa = *(const float4*)src;
      const float4 bb = *(const float4*)(src + 4);
      half8 hh;
      hh[0]=(_Float16)aa.x; hh[1]=(_Float16)aa.y; hh[2]=(_Float16)aa.z; hh[3]=(_Float16)aa.w;
      hh[4]=(_Float16)bb.x; hh[5]=(_Float16)bb.y; hh[6]=(_Float16)bb.z; hh[7]=(_Float16)bb.w;
      wf[g][s] = hh;
    }
  }
  f32x4 bias4[4];
  #pragma unroll
  for (int g = 0; g < 4; ++g)
    #pragma unroll
    for (int r = 0; r < 4; ++r){
      const int row = g * HID + u0 + kq * 4 + r;
      bias4[g][r] = bih[row] + bhh[row];
    }

  // ---- staging thread mapping: 16 rows x 128 f16
  const int sb = tid >> 5;   // 0..15 batch row
  const int sk = tid & 31;   // col group (8B)

  auto xaddr = [&](int t){
    return (const float4*)(x + ((size_t)(b0 + sb) * SEQ + t) * HID + sk * 4);
  };
  auto raddr = [&](int t){
    return (u64*)(rin + ((size_t)(t & (RING-1)) * BATCH + b0 + sb) * 64 + sk * 2);
  };

  float4 pfa, pfb;         // MODE 0: x prefetch (cur / nxt)
  u64    pga = 0, pgb = 0; // MODE 1/2: ring prefetch

  int fseen = 0, fpend = 0, dseen = 0;

  // ---- prologue: SKEW lag, stage data(0) -> act0, preload data(1)
  if constexpr (MODE != 0){
    fseen = aload(src_ready);
    while (fseen < SKEW){ __builtin_amdgcn_s_sleep(8); fseen = aload(src_ready); }
  }
  if constexpr (MODE == 0){
    const float4 v = *xaddr(0);
    uint2 p; p.x = pack2f(v.x, v.y); p.y = pack2f(v.z, v.w);
    *(uint2*)(act0 + sb * ROWB + sk * 8) = p;
    pfa = *xaddr(1);
  } else {
    const u64 v = __hip_atomic_load(raddr(0), __ATOMIC_RELAXED, __HIP_MEMORY_SCOPE_AGENT);
    *(u64*)(act0 + sb * ROWB + sk * 8) = v;
    pga = __hip_atomic_load(raddr(1), __ATOMIC_RELAXED, __HIP_MEMORY_SCOPE_AGENT);
    fpend = aload(src_ready);
  }
  if (tid < 256)
    *(uint4*)(act0 + (tid >> 4) * ROWB + 256 + (tid & 15) * 16) = make_uint4(0u,0u,0u,0u);
  __syncthreads();   // prologue: full drain once

  f32x4 c4 = {0.f, 0.f, 0.f, 0.f};
  const int boff = rm * ROWB + kq * 16;
  int cur = 0;

  uint2 hp = {0u, 0u};     // deferred-store state (h of step t-1, f16 packed)

  for (int t = 0; t < SEQ; ++t){
    char* bc = cur ? act1 : act0;
    char* bn = cur ? act0 : act1;
    const int tn   = t + 1;
    const int tpre = t + 2;

    // ---- PHASE 1: all VMEM issue (latency hides under MFMA phase) ----
    // deferred global store of h(t-1)
    if (t > 0){
      if constexpr (MODE != 2){
        const u64 hp64 = ((u64)hp.y << 32) | (u64)hp.x;
        u64* p = (u64*)(rout + ((size_t)((t-1) & (RING-1)) * BATCH + b0 + rm) * 64 + (u0 >> 1) + kq * 2);
        __hip_atomic_store(p, hp64, __ATOMIC_RELAXED, __HIP_MEMORY_SCOPE_AGENT);
      } else {
        const size_t yb = ((size_t)(t-1) * HID + u0 + kq * 4) * BATCH + b0 + rm;
        y[yb]             = unpk(hp.x, 0);
        y[yb + BATCH]     = unpk(hp.x, 1);
        y[yb + 2 * BATCH] = unpk(hp.y, 0);
        y[yb + 3 * BATCH] = unpk(hp.y, 1);
      }
    }
    // continuous ready publish: value t-2 (stores issued >=1.5 steps ago,
    // far beyond store-to-L2 latency; r11-verified protocol)
    if (tid == 0){
      if constexpr (MODE != 2){
        if (t >= 3)
          __hip_atomic_store(dst_ready, t - 2, __ATOMIC_RELAXED, __HIP_MEMORY_SCOPE_AGENT);
      }
      if constexpr (MODE != 0){
        if ((t & (CH-1)) == 0 && t > 0)
          __hip_atomic_store(src_done, t >> 3, __ATOMIC_RELAXED, __HIP_MEMORY_SCOPE_AGENT);
      }
    }
    // back-pressure: cached; blocking refresh only if bound violated
    if constexpr (MODE != 2){
      if ((t & (CH-1)) == 0 && t >= RING){
        const int need = (t >> 3) - 7;
        if (dseen < need){
          dseen = aload(dst_done);
          while (dseen < need){ __builtin_amdgcn_s_sleep(8); dseen = aload(dst_done); }
        }
      }
    }
    // pipelined flag check + 2-deep prefetch issue (slot t+2)
    if constexpr (MODE != 0){
      if (fpend > fseen) fseen = fpend;
      fpend = aload(src_ready);
      if (tpre < SEQ && fseen < tpre + 1){
        fseen = aload(src_ready);
        while (fseen < tpre + 1){ __builtin_amdgcn_s_sleep(2); fseen = aload(src_ready); }
      }
    }
    if (tpre < SEQ){
      if constexpr (MODE == 0) pfb = *xaddr(tpre);
      else pgb = __hip_atomic_load(raddr(tpre), __ATOMIC_RELAXED, __HIP_MEMORY_SCOPE_AGENT);
    }

    // ---- PHASE 2: fused gate GEMM (K=256), acc init = bias ----
    __builtin_amdgcn_s_setprio(1);
    f32x4 a0 = bias4[0], a1 = bias4[1], a2 = bias4[2], a3 = bias4[3];
    #pragma unroll
    for (int s = 0; s < 8; ++s){
      const half8 bf = *(const half8*)(bc + boff + s * 64);
      a0 = __builtin_amdgcn_mfma_f32_16x16x32_f16(wf[0][s], bf, a0, 0, 0, 0);
      a1 = __builtin_amdgcn_mfma_f32_16x16x32_f16(wf[1][s], bf, a1, 0, 0, 0);
      a2 = __builtin_amdgcn_mfma_f32_16x16x32_f16(wf[2][s], bf, a2, 0, 0, 0);
      a3 = __builtin_amdgcn_mfma_f32_16x16x32_f16(wf[3][s], bf, a3, 0, 0, 0);
    }

    // ---- PHASE 3: x(t+1) staging -> bn (LDS pipe idle during the trans
    // burst below; these writes drain for free). bn's old contents were
    // last read before the PREVIOUS barrier -> safe.
    if (tn < SEQ){
      if constexpr (MODE == 0){
        uint2 p; p.x = pack2f(pfa.x, pfa.y); p.y = pack2f(pfa.z, pfa.w);
        *(uint2*)(bn + sb * ROWB + sk * 8) = p;
      } else {
        *(u64*)(bn + sb * ROWB + sk * 8) = pga;
      }
    }

    // ---- PHASE 4: elementwise (trans burst), lane holds i,f,g,o x 4 units
    float hvr[4];
    #pragma unroll
    for (int r = 0; r < 4; ++r){
      const float ii = sigm(a0[r]), ff = sigm(a1[r]);
      const float gg = tanh_(a2[r]), oo = sigm(a3[r]);
      c4[r] = ff * c4[r] + ii * gg;
      hvr[r] = oo * tanh_(c4[r]);
    }
    __builtin_amdgcn_s_setprio(0);
    hp.x = pack2f(hvr[0], hvr[1]);
    hp.y = pack2f(hvr[2], hvr[3]);

    // ---- PHASE 5: h(t) -> bn (next step's critical input) ----
    *(uint2*)(bn + rm * ROWB + 256 + u0 * 2 + kq * 8) = hp;

    BARRIER_LDS();
    pfa = pfb; pga = pgb;
    cur ^= 1;
  }

  // ---- tail: flush step SEQ-1, full drain, final publishes
  if constexpr (MODE != 2){
    const u64 hp64 = ((u64)hp.y << 32) | (u64)hp.x;
    u64* p = (u64*)(rout + ((size_t)((SEQ-1) & (RING-1)) * BATCH + b0 + rm) * 64 + (u0 >> 1) + kq * 2);
    __hip_atomic_store(p, hp64, __ATOMIC_RELAXED, __HIP_MEMORY_SCOPE_AGENT);
  } else {
    const size_t yb = ((size_t)(SEQ-1) * HID + u0 + kq * 4) * BATCH + b0 + rm;
    y[yb]             = unpk(hp.x, 0);
    y[yb + BATCH]     = unpk(hp.x, 1);
    y[yb + 2 * BATCH] = unpk(hp.y, 0);
    y[yb + 3 * BATCH] = unpk(hp.y, 1);
  }
  __syncthreads();   // tail: FULL drain -> final flags valid
  if (tid == 0){
    if constexpr (MODE != 2)
      __hip_atomic_store(dst_ready, SEQ, __ATOMIC_RELAXED, __HIP_MEMORY_SCOPE_AGENT);
    if constexpr (MODE != 0)
      __hip_atomic_store(src_done, SEQ / CH, __ATOMIC_RELAXED, __HIP_MEMORY_SCOPE_AGENT);
  }
}

// Grid: 96 blocks (3 layers x 32 tiles) x 512 threads, (512,2): the proven
// codegen shape. Allocator facts measured this session: 512-thr kernels pin
// at 128 VGPR ((512,2)==(512,1)), 1024-thr at 64 — exceeding spills.
__global__ __launch_bounds__(512, 2) void lstm_pipe(
    const float* W0i, const float* W0h, const float* b0i, const float* b0h,
    const float* W1i, const float* W1h, const float* b1i, const float* b1h,
    const float* W2i, const float* W2h, const float* b2i, const float* b2h,
    const float* x, float* y, uint32_t* ring, int* flags)
{
  const int layer = blockIdx.x >> 5;   // 0,1,2
  const int tile  = blockIdx.x & 31;
  const int b0    = tile * BT;

  __shared__ char act[2][BT * ROWB];

  uint32_t* r0 = ring;                                 // boundary 0: L0 -> L1
  uint32_t* r1 = ring + (size_t)RING * BATCH * 64;     // boundary 1: L1 -> L2

  int* p0 = flags + (0 * NTILE + tile) * FPAD;   // ready, boundary 0
  int* p1 = flags + (1 * NTILE + tile) * FPAD;   // ready, boundary 1
  int* c0 = flags + (2 * NTILE + tile) * FPAD;   // done,  boundary 0
  int* c1 = flags + (3 * NTILE + tile) * FPAD;   // done,  boundary 1

  if (layer == 0){
    run_layer<0>(W0i, W0h, b0i, b0h, x, nullptr, r0, nullptr,
                 nullptr, nullptr, p0, c0, b0, act[0], act[1]);
  } else if (layer == 1){
    run_layer<1>(W1i, W1h, b1i, b1h, nullptr, r0, r1, nullptr,
                 p0, c0, p1, c1, b0, act[0], act[1]);
  } else {
    run_layer<2>(W2i, W2h, b2i, b2h, nullptr, r1, nullptr, y,
                 p1, c1, nullptr, nullptr, b0, act[0], act[1]);
  }
}

extern "C" void kernel_launch(void* const* d_in, const int* in_sizes, int n_in,
                              void* d_out, int out_size, void* d_ws, size_t ws_size,
                              hipStream_t stream) {
  const float* x    = (const float*)d_in[0];
  const float* Wih0 = (const float*)d_in[1];
  const float* Whh0 = (const float*)d_in[2];
  const float* bih0 = (const float*)d_in[3];
  const float* bhh0 = (const float*)d_in[4];
  const float* Wih1 = (const float*)d_in[5];
  const float* Whh1 = (const float*)d_in[6];
  const float* bih1 = (const float*)d_in[7];
  const float* bhh1 = (const float*)d_in[8];
  const float* Wih2 = (const float*)d_in[9];
  const float* Whh2 = (const float*)d_in[10];
  const float* bih2 = (const float*)d_in[11];
  const float* bhh2 = (const float*)d_in[12];

  float* out = (float*)d_out;
  uint32_t* ring = (uint32_t*)d_ws;
  const size_t ring_bytes = (size_t)2 * RING * BATCH * 64 * 4;   // 16 MiB
  int* flags = (int*)((char*)d_ws + ring_bytes);

  hipMemsetAsync(flags, 0, 4 * NTILE * FPAD * sizeof(int), stream);

  dim3 grid(3 * NTILE), block(512);
  lstm_pipe<<<grid, block, 0, stream>>>(
      Wih0, Whh0, bih0, bhh0, Wih1, Whh1, bih1, bhh1, Wih2, Whh2, bih2, bhh2,
      x, out, ring, flags);
}